// Round 2
// 7526.937 us; speedup vs baseline: 1.7568x; 1.7568x over previous
//
#include <hip/hip_runtime.h>

#define NUM_E 38
#define FDIM 1140
#define NPAIRS 50000
#define FPAD 1152           // 1140 padded to 36*32
#define NPAD 50048          // 50000 padded to 391*128
#define BM 128
#define BN 128
#define BJ 32
#define NCHUNK 9            // 1152/128 (fp32 fallback)
#define NJIT 36             // 1152/32
#define NTILES 391          // 50048/128

typedef short short8 __attribute__((ext_vector_type(8)));
typedef short short4v __attribute__((ext_vector_type(4)));
typedef float float4v __attribute__((ext_vector_type(4)));

__device__ __forceinline__ short f2bf(float f) {
  union { float f; unsigned u; } v; v.f = f;
  unsigned r = v.u + 0x7FFFu + ((v.u >> 16) & 1u);   // RNE
  return (short)(r >> 16);
}
__device__ __forceinline__ float bf2f(short s) {
  union { unsigned u; float f; } v; v.u = ((unsigned)(unsigned short)s) << 16;
  return v.f;
}
__device__ __forceinline__ void gl2lds16(const short* g, short* l) {
  __builtin_amdgcn_global_load_lds(
      (const __attribute__((address_space(1))) void*)g,
      (__attribute__((address_space(3))) void*)l, 16, 0, 0);
}

// ---- conversion: fp32 [groups][R][C] -> bf16 [groups][Rpad][Cpad], zero-padded
__global__ void __launch_bounds__(256) convpad_kernel(
    const float* __restrict__ src, short* __restrict__ dst,
    int R, int Rpad, int C, int Cpad, int groups)
{
  const int cpc = Cpad >> 3;                       // 8-elem chunks per row
  const long total = (long)groups * Rpad * cpc;
  for (long idx = (long)blockIdx.x * blockDim.x + threadIdx.x; idx < total;
       idx += (long)gridDim.x * blockDim.x) {
    const int g   = (int)(idx / ((long)Rpad * cpc));
    const long rem = idx - (long)g * Rpad * cpc;
    const int row = (int)(rem / cpc);
    const int j0  = ((int)(rem - (long)row * cpc)) << 3;
    short8 o = (short8){0,0,0,0,0,0,0,0};
    if (row < R) {
      const float* s = src + ((size_t)g * R + row) * C + j0;
      if (j0 + 8 <= C) {
        float4v v0 = *(const float4v*)s;
        float4v v1 = *(const float4v*)(s + 4);
        o = (short8){f2bf(v0[0]), f2bf(v0[1]), f2bf(v0[2]), f2bf(v0[3]),
                     f2bf(v1[0]), f2bf(v1[1]), f2bf(v1[2]), f2bf(v1[3])};
      } else {
#pragma unroll
        for (int t = 0; t < 8; ++t)
          o[t] = (j0 + t < C) ? f2bf(s[t]) : (short)0;
      }
    }
    *(short8*)(dst + ((size_t)g * Rpad + row) * Cpad + j0) = o;
  }
}

// ===========================================================================
// Main kernel. Per block: one (e, i-tile[128]). k (rows of W_e) processed in
// groups of PP*128 so each staged A j-chunk is reused for PP k-chunks
// (E global re-reads: 9 -> 5 passes). Waves tiled 2x2 (wr,wc): each wave
// owns a 64x64 quadrant -> 12 ds_read_b128 per 32 MFMAs.
// LDS XOR-swizzle (both-sides, rule #21): logical 16B chunk c of local row r
// stored at c ^ ((r>>1)&3). global_load_lds dest stays linear; the SOURCE
// address is pre-permuted; ds_reads apply the same XOR. Verified: each
// 16-lane phase spreads across all 8 bank-groups, 2-way (free).
// ===========================================================================
template <int PP>
__device__ __forceinline__ void nc_group(
    const short* __restrict__ Abase,   // Ebf + i0*FPAD
    const short* __restrict__ Bbase,   // Wbf + e*FPAD*FPAD
    const short* __restrict__ Sbase,   // Sbf + i0*FPAD
    float (&out_acc)[16],
    short* lds_a, short* lds_b, float* lds_red,
    int k0, int wave, int lane)
{
  const int l15  = lane & 15;
  const int quad = lane >> 4;
  const int wr   = wave >> 1;
  const int wc   = wave & 1;
  const int sr   = lane >> 2;                                 // staging row in slab
  const int scz  = ((lane & 3) ^ ((lane >> 3) & 3)) << 3;     // pre-swizzled src col
  const int rc   = (quad ^ ((l15 >> 1) & 3)) << 3;            // swizzled read chunk
  const int a_off = (((wr << 6) + l15) << 5) + rc;            // shorts; + mi<<9
  const int b_off = (((wc << 6) + l15) << 5) + rc;            // shorts; + p<<12 + ni<<9

  float4v acc[PP][4][4];
#pragma unroll
  for (int p = 0; p < PP; ++p)
#pragma unroll
    for (int mi = 0; mi < 4; ++mi)
#pragma unroll
      for (int ni = 0; ni < 4; ++ni)
        acc[p][mi][ni] = (float4v){0.f, 0.f, 0.f, 0.f};

  for (int jt = 0; jt < NJIT; ++jt) {
    const int j0 = jt << 5;
    // stage A: 8 slabs of 16 rows x 32 cols, 2 per wave
#pragma unroll
    for (int rd = 0; rd < 2; ++rd) {
      const int slab = (wave << 1) + rd;
      gl2lds16(Abase + (size_t)((slab << 4) + sr) * FPAD + j0 + scz,
               lds_a + (slab << 9));
    }
    // stage B: PP*8 slabs (PP k-chunks of 128 W-rows), 2*PP per wave
#pragma unroll
    for (int rd = 0; rd < 2 * PP; ++rd) {
      const int bslab = wave * (2 * PP) + rd;
      gl2lds16(Bbase + (size_t)(k0 + (bslab << 4) + sr) * FPAD + j0 + scz,
               lds_b + (bslab << 9));
    }
    __syncthreads();

    short8 af[4], bfr[PP][4];
#pragma unroll
    for (int mi = 0; mi < 4; ++mi)
      af[mi] = *(const short8*)(lds_a + a_off + (mi << 9));
#pragma unroll
    for (int p = 0; p < PP; ++p)
#pragma unroll
      for (int ni = 0; ni < 4; ++ni)
        bfr[p][ni] = *(const short8*)(lds_b + (p << 12) + b_off + (ni << 9));

#pragma unroll
    for (int p = 0; p < PP; ++p)
#pragma unroll
      for (int mi = 0; mi < 4; ++mi)
#pragma unroll
        for (int ni = 0; ni < 4; ++ni)
          acc[p][mi][ni] = __builtin_amdgcn_mfma_f32_16x16x32_bf16(
              af[mi], bfr[p][ni], acc[p][mi][ni], 0, 0, 0);
    __syncthreads();
  }

  // fused epilogue: out_acc[row] += sum_k R[row,k] * S[row,k] for this k-group.
  // C/D layout: col(k) = l15, row = quad*4 + r (within the 16x16 fragment).
  // Each wave covers 64 k-cols (its wc half) -> cross-wc combine via lds_red.
#pragma unroll
  for (int p = 0; p < PP; ++p) {
#pragma unroll
    for (int mi = 0; mi < 4; ++mi) {
#pragma unroll
      for (int r = 0; r < 4; ++r) {
        const int il = (wr << 6) + (mi << 4) + (quad << 2) + r;
        const short* srow = Sbase + (size_t)il * FPAD + k0 + (p << 7) + (wc << 6);
        float s = 0.f;
#pragma unroll
        for (int ni = 0; ni < 4; ++ni)
          s += acc[p][mi][ni][r] * bf2f(srow[(ni << 4) + l15]);
        s += __shfl_xor(s, 1);
        s += __shfl_xor(s, 2);
        s += __shfl_xor(s, 4);
        s += __shfl_xor(s, 8);
        if (wc == 0) {
          out_acc[(mi << 2) + r] += s;
        } else if (l15 == 0) {
          lds_red[il] = s;
        }
      }
    }
    __syncthreads();
    if (wc == 0) {
#pragma unroll
      for (int mi = 0; mi < 4; ++mi)
#pragma unroll
        for (int r = 0; r < 4; ++r)
          out_acc[(mi << 2) + r] +=
              lds_red[(wr << 6) + (mi << 4) + (quad << 2) + r];
    }
    __syncthreads();
  }
}

__global__ void __launch_bounds__(256, 2) kway_bf16_kernel(
    const short* __restrict__ Wbf,   // [38][1152][1152]
    const short* __restrict__ Sbf,   // [50048][1152]
    const short* __restrict__ Ebf,   // [50048][1152]
    float* __restrict__ out)
{
  __shared__ short lds_a[BM * BJ];        // 8 KB
  __shared__ short lds_b[2 * BM * BJ];    // 16 KB (PP=2 k-chunks)
  __shared__ float lds_red[BM];           // 512 B cross-wave combine

  const int e  = blockIdx.x / NTILES;     // e-major: W_e stays L2-hot per XCD
  const int it = blockIdx.x % NTILES;
  const int i0 = it * BM;

  const int tid  = threadIdx.x;
  const int wave = tid >> 6;
  const int lane = tid & 63;

  const short* Abase = Ebf + (size_t)i0 * FPAD;
  const short* Bbase = Wbf + (size_t)e * FPAD * FPAD;
  const short* Sbase = Sbf + (size_t)i0 * FPAD;

  float out_acc[16];
#pragma unroll
  for (int x = 0; x < 16; ++x) out_acc[x] = 0.f;

  // k groups: 4 x (PP=2, 256 rows) + 1 x (PP=1, 128 rows) = 1152
  for (int g = 0; g < 4; ++g)
    nc_group<2>(Abase, Bbase, Sbase, out_acc, lds_a, lds_b, lds_red,
                g << 8, wave, lane);
  nc_group<1>(Abase, Bbase, Sbase, out_acc, lds_a, lds_b, lds_red,
              1024, wave, lane);

  // wc==0 waves (0 and 2) hold the full sums for rows wr*64 .. wr*64+63
  if ((wave & 1) == 0 && (lane & 15) == 0) {
    const int wr = wave >> 1;
    const int quad = lane >> 4;
#pragma unroll
    for (int mi = 0; mi < 4; ++mi)
#pragma unroll
      for (int r = 0; r < 4; ++r) {
        const int gi = i0 + (wr << 6) + (mi << 4) + (quad << 2) + r;
        if (gi < NPAIRS) out[(size_t)e * NPAIRS + gi] = out_acc[(mi << 2) + r];
      }
  }
}

// ================= fallback fp32 path (round-1 kernel, known-good) =========
#define LSTRIDE 40
__global__ void __launch_bounds__(256) kway_fp32_kernel(
    const float* __restrict__ start_emb,
    const float* __restrict__ end_emb,
    const float* __restrict__ weights,
    float* __restrict__ out)
{
  __shared__ short lds_a[BM * LSTRIDE];
  __shared__ short lds_b[BN * LSTRIDE];

  const int e  = blockIdx.x % NUM_E;
  const int it = blockIdx.x / NUM_E;
  const int i0 = it * BM;

  const int tid  = threadIdx.x;
  const int wave = tid >> 6;
  const int lane = tid & 63;
  const int l15  = lane & 15;
  const int quad = lane >> 4;

  const float* We = weights + (size_t)e * FDIM * FDIM;
  const int srow = tid >> 3;
  const int scol = (tid & 7) << 2;

  float out_acc[8];
#pragma unroll
  for (int x = 0; x < 8; ++x) out_acc[x] = 0.f;

  for (int nc = 0; nc < NCHUNK; ++nc) {
    const int k0 = nc * BN;
    float4v acc[2][8];
#pragma unroll
    for (int mi = 0; mi < 2; ++mi)
#pragma unroll
      for (int ni = 0; ni < 8; ++ni)
        acc[mi][ni] = (float4v){0.f, 0.f, 0.f, 0.f};

    for (int jt = 0; jt < NJIT; ++jt) {
      const int gj = jt * BJ + scol;
      const bool jok = gj < FDIM;
      float4v av[4], bv[4];
#pragma unroll
      for (int rr = 0; rr < 4; ++rr) {
        const int row = (rr << 5) + srow;
        const int gi = i0 + row;
        av[rr] = (float4v){0.f, 0.f, 0.f, 0.f};
        if (jok && gi < NPAIRS)
          av[rr] = *(const float4v*)(end_emb + (size_t)gi * FDIM + gj);
        const int gk = k0 + row;
        bv[rr] = (float4v){0.f, 0.f, 0.f, 0.f};
        if (jok && gk < FDIM)
          bv[rr] = *(const float4v*)(We + (size_t)gk * FDIM + gj);
      }
#pragma unroll
      for (int rr = 0; rr < 4; ++rr) {
        const int row = (rr << 5) + srow;
        short4v a4 = { f2bf(av[rr][0]), f2bf(av[rr][1]), f2bf(av[rr][2]), f2bf(av[rr][3]) };
        *(short4v*)(&lds_a[row * LSTRIDE + scol]) = a4;
        short4v b4 = { f2bf(bv[rr][0]), f2bf(bv[rr][1]), f2bf(bv[rr][2]), f2bf(bv[rr][3]) };
        *(short4v*)(&lds_b[row * LSTRIDE + scol]) = b4;
      }
      __syncthreads();

      short8 afrag[2], bfrag[8];
#pragma unroll
      for (int mi = 0; mi < 2; ++mi)
        afrag[mi] = *(short8*)(&lds_a[((wave << 5) + (mi << 4) + l15) * LSTRIDE + (quad << 3)]);
#pragma unroll
      for (int ni = 0; ni < 8; ++ni)
        bfrag[ni] = *(short8*)(&lds_b[((ni << 4) + l15) * LSTRIDE + (quad << 3)]);
#pragma unroll
      for (int mi = 0; mi < 2; ++mi)
#pragma unroll
        for (int ni = 0; ni < 8; ++ni)
          acc[mi][ni] = __builtin_amdgcn_mfma_f32_16x16x32_bf16(
              afrag[mi], bfrag[ni], acc[mi][ni], 0, 0, 0);
      __syncthreads();
    }

#pragma unroll
    for (int mi = 0; mi < 2; ++mi) {
#pragma unroll
      for (int r = 0; r < 4; ++r) {
        const int gi = i0 + (wave << 5) + (mi << 4) + (quad << 2) + r;
        const bool iok = gi < NPAIRS;
        float s = 0.f;
#pragma unroll
        for (int ni = 0; ni < 8; ++ni) {
          const int k = k0 + (ni << 4) + l15;
          const float sv = (iok && k < FDIM) ? start_emb[(size_t)gi * FDIM + k] : 0.f;
          s += acc[mi][ni][r] * sv;
        }
        out_acc[(mi << 2) + r] += s;
      }
    }
  }

#pragma unroll
  for (int x = 0; x < 8; ++x) {
    float v = out_acc[x];
    v += __shfl_xor(v, 1);
    v += __shfl_xor(v, 2);
    v += __shfl_xor(v, 4);
    v += __shfl_xor(v, 8);
    out_acc[x] = v;
  }
  if (l15 == 0) {
#pragma unroll
    for (int mi = 0; mi < 2; ++mi)
#pragma unroll
      for (int r = 0; r < 4; ++r) {
        const int gi = i0 + (wave << 5) + (mi << 4) + (quad << 2) + r;
        if (gi < NPAIRS) out[(size_t)e * NPAIRS + gi] = out_acc[(mi << 2) + r];
      }
  }
}

extern "C" void kernel_launch(void* const* d_in, const int* in_sizes, int n_in,
                              void* d_out, int out_size, void* d_ws, size_t ws_size,
                              hipStream_t stream) {
  const float* start_emb = (const float*)d_in[0];
  const float* end_emb   = (const float*)d_in[1];
  const float* weights   = (const float*)d_in[2];
  float* out = (float*)d_out;

  const size_t W_ELEMS = (size_t)NUM_E * FPAD * FPAD;   // 50,429,952
  const size_t EMB_ELEMS = (size_t)NPAD * FPAD;         // 57,655,296
  const size_t need = (W_ELEMS + 2 * EMB_ELEMS) * sizeof(short);  // ~331.5 MB

  if (ws_size >= need) {
    short* Wbf = (short*)d_ws;
    short* Sbf = Wbf + W_ELEMS;
    short* Ebf = Sbf + EMB_ELEMS;

    {
      const long wt = (long)NUM_E * FPAD * (FPAD >> 3);
      convpad_kernel<<<(int)((wt + 255) / 256), 256, 0, stream>>>(
          weights, Wbf, FDIM, FPAD, FDIM, FPAD, NUM_E);
      const long et = (long)NPAD * (FPAD >> 3);
      convpad_kernel<<<(int)((et + 255) / 256), 256, 0, stream>>>(
          start_emb, Sbf, NPAIRS, NPAD, FDIM, FPAD, 1);
      convpad_kernel<<<(int)((et + 255) / 256), 256, 0, stream>>>(
          end_emb, Ebf, NPAIRS, NPAD, FDIM, FPAD, 1);
    }
    kway_bf16_kernel<<<NUM_E * NTILES, 256, 0, stream>>>(Wbf, Sbf, Ebf, out);
  } else {
    kway_fp32_kernel<<<NUM_E * NTILES, 256, 0, stream>>>(
        start_emb, end_emb, weights, out);
  }
}

// Round 3
// 7513.165 us; speedup vs baseline: 1.7600x; 1.0018x over previous
//
#include <hip/hip_runtime.h>

#define NUM_E 38
#define FDIM 1140
#define NPAIRS 50000
#define FPAD 1152           // 1140 padded to 36*32
#define NPAD 50048          // 50000 padded to 391*128
#define BM 128
#define BN 128
#define BJ 32
#define NCHUNK 9            // 1152/128 (fp32 fallback)
#define NJIT 36             // 1152/32
#define NTILES 391          // 50048/128

typedef short short8 __attribute__((ext_vector_type(8)));
typedef short short4v __attribute__((ext_vector_type(4)));
typedef float float4v __attribute__((ext_vector_type(4)));

__device__ __forceinline__ short f2bf(float f) {
  union { float f; unsigned u; } v; v.f = f;
  unsigned r = v.u + 0x7FFFu + ((v.u >> 16) & 1u);   // RNE
  return (short)(r >> 16);
}
__device__ __forceinline__ float bf2f(short s) {
  union { unsigned u; float f; } v; v.u = ((unsigned)(unsigned short)s) << 16;
  return v.f;
}
__device__ __forceinline__ void gl2lds16(const short* g, short* l) {
  __builtin_amdgcn_global_load_lds(
      (const __attribute__((address_space(1))) void*)g,
      (__attribute__((address_space(3))) void*)l, 16, 0, 0);
}

// ---- conversion: fp32 [groups][R][C] -> bf16 [groups][Rpad][Cpad], zero-padded
__global__ void __launch_bounds__(256) convpad_kernel(
    const float* __restrict__ src, short* __restrict__ dst,
    int R, int Rpad, int C, int Cpad, int groups)
{
  const int cpc = Cpad >> 3;                       // 8-elem chunks per row
  const long total = (long)groups * Rpad * cpc;
  for (long idx = (long)blockIdx.x * blockDim.x + threadIdx.x; idx < total;
       idx += (long)gridDim.x * blockDim.x) {
    const int g   = (int)(idx / ((long)Rpad * cpc));
    const long rem = idx - (long)g * Rpad * cpc;
    const int row = (int)(rem / cpc);
    const int j0  = ((int)(rem - (long)row * cpc)) << 3;
    short8 o = (short8){0,0,0,0,0,0,0,0};
    if (row < R) {
      const float* s = src + ((size_t)g * R + row) * C + j0;
      if (j0 + 8 <= C) {
        float4v v0 = *(const float4v*)s;
        float4v v1 = *(const float4v*)(s + 4);
        o = (short8){f2bf(v0[0]), f2bf(v0[1]), f2bf(v0[2]), f2bf(v0[3]),
                     f2bf(v1[0]), f2bf(v1[1]), f2bf(v1[2]), f2bf(v1[3])};
      } else {
#pragma unroll
        for (int t = 0; t < 8; ++t)
          o[t] = (j0 + t < C) ? f2bf(s[t]) : (short)0;
      }
    }
    *(short8*)(dst + ((size_t)g * Rpad + row) * Cpad + j0) = o;
  }
}

// ===========================================================================
// Main kernel. Per block: one (e, i-tile[128]); k in groups of PP*128 (A
// reused PP-fold). Waves 2x2, each owns a 64x64 quadrant.
// LDS XOR-swizzle (both-sides, rule #21): verified round 2 — conflicts 0.
// Round 3: software-pipelined jt loop (T3/T4-lite). Double-buffered LDS;
// stage for jt+1 issued at top of iteration jt; counted s_waitcnt vmcnt(N)
// waits only for buf[cur]'s loads (issued one full iteration earlier, so
// even L3-miss latency ~900cy is covered); raw s_barrier pair per jt, no
// vmcnt(0) drain in the steady-state loop.
// ===========================================================================
template <int PP>
__device__ __forceinline__ void nc_group(
    const short* __restrict__ Abase,   // Ebf + i0*FPAD
    const short* __restrict__ Bbase,   // Wbf + e*FPAD*FPAD
    const short* __restrict__ Sbase,   // Sbf + i0*FPAD
    float (&out_acc)[16],
    short* lds_a, short* lds_b, float* lds_red,
    int k0, int wave, int lane)
{
  const int l15  = lane & 15;
  const int quad = lane >> 4;
  const int wr   = wave >> 1;
  const int wc   = wave & 1;
  const int sr   = lane >> 2;                                 // staging row in slab
  const int scz  = ((lane & 3) ^ ((lane >> 3) & 3)) << 3;     // pre-swizzled src col
  const int rc   = (quad ^ ((l15 >> 1) & 3)) << 3;            // swizzled read chunk
  const int a_off = (((wr << 6) + l15) << 5) + rc;            // shorts; + mi<<9
  const int b_off = (((wc << 6) + l15) << 5) + rc;            // shorts; + p<<12 + ni<<9

  // per-slab global base pointers; advance by 32 shorts per jt
  const short* ga[2];
  const short* gb[2 * PP];
#pragma unroll
  for (int rd = 0; rd < 2; ++rd)
    ga[rd] = Abase + (size_t)((((wave << 1) + rd) << 4) + sr) * FPAD + scz;
#pragma unroll
  for (int rd = 0; rd < 2 * PP; ++rd)
    gb[rd] = Bbase + (size_t)(k0 + ((wave * 2 * PP + rd) << 4) + sr) * FPAD + scz;

  float4v acc[PP][4][4];
#pragma unroll
  for (int p = 0; p < PP; ++p)
#pragma unroll
    for (int mi = 0; mi < 4; ++mi)
#pragma unroll
      for (int ni = 0; ni < 4; ++ni)
        acc[p][mi][ni] = (float4v){0.f, 0.f, 0.f, 0.f};

  auto stage = [&](int jtn, int buf) {
    const int j0 = jtn << 5;
    short* la = lds_a + (buf << 12);             // buf stride 4096 shorts (8 KB)
    short* lb = lds_b + buf * (PP << 12);        // buf stride PP*4096 shorts
#pragma unroll
    for (int rd = 0; rd < 2; ++rd)
      gl2lds16(ga[rd] + j0, la + (((wave << 1) + rd) << 9));
#pragma unroll
    for (int rd = 0; rd < 2 * PP; ++rd)
      gl2lds16(gb[rd] + j0, lb + ((wave * 2 * PP + rd) << 9));
  };

  auto compute = [&](int buf) {
    const short* la = lds_a + (buf << 12);
    const short* lb = lds_b + buf * (PP << 12);
    short8 af[4], bfr[PP][4];
#pragma unroll
    for (int mi = 0; mi < 4; ++mi)
      af[mi] = *(const short8*)(la + a_off + (mi << 9));
#pragma unroll
    for (int p = 0; p < PP; ++p)
#pragma unroll
      for (int ni = 0; ni < 4; ++ni)
        bfr[p][ni] = *(const short8*)(lb + (p << 12) + b_off + (ni << 9));
#pragma unroll
    for (int p = 0; p < PP; ++p)
#pragma unroll
      for (int mi = 0; mi < 4; ++mi)
#pragma unroll
        for (int ni = 0; ni < 4; ++ni)
          acc[p][mi][ni] = __builtin_amdgcn_mfma_f32_16x16x32_bf16(
              af[mi], bfr[p][ni], acc[p][mi][ni], 0, 0, 0);
  };

  // ---- pipelined jt loop: 1-iteration-ahead prefetch, counted vmcnt ----
  stage(0, 0);
  int cur = 0;
  for (int jt = 0; jt < NJIT - 1; ++jt) {
    stage(jt + 1, cur ^ 1);                       // issue next-tile loads early
    // wait only for buf[cur]'s (2+2PP) loads; the (2+2PP) just-issued stay in flight
    asm volatile("s_waitcnt vmcnt(%0)" :: "i"(2 + 2 * PP) : "memory");
    __builtin_amdgcn_s_barrier();                 // buf[cur] visible to all waves
    compute(cur);
    __builtin_amdgcn_s_barrier();                 // all waves consumed buf[cur]
    cur ^= 1;
  }
  asm volatile("s_waitcnt vmcnt(0)" ::: "memory");
  __builtin_amdgcn_s_barrier();
  compute(cur);
  __builtin_amdgcn_s_barrier();

  // fused epilogue: out_acc[row] += sum_k R[row,k] * S[row,k] for this k-group.
  // C/D layout: col(k) = l15, row = quad*4 + r (within the 16x16 fragment).
#pragma unroll
  for (int p = 0; p < PP; ++p) {
#pragma unroll
    for (int mi = 0; mi < 4; ++mi) {
#pragma unroll
      for (int r = 0; r < 4; ++r) {
        const int il = (wr << 6) + (mi << 4) + (quad << 2) + r;
        const short* srow = Sbase + (size_t)il * FPAD + k0 + (p << 7) + (wc << 6);
        float s = 0.f;
#pragma unroll
        for (int ni = 0; ni < 4; ++ni)
          s += acc[p][mi][ni][r] * bf2f(srow[(ni << 4) + l15]);
        s += __shfl_xor(s, 1);
        s += __shfl_xor(s, 2);
        s += __shfl_xor(s, 4);
        s += __shfl_xor(s, 8);
        if (wc == 0) {
          out_acc[(mi << 2) + r] += s;
        } else if (l15 == 0) {
          lds_red[il] = s;
        }
      }
    }
    __syncthreads();
    if (wc == 0) {
#pragma unroll
      for (int mi = 0; mi < 4; ++mi)
#pragma unroll
        for (int r = 0; r < 4; ++r)
          out_acc[(mi << 2) + r] +=
              lds_red[(wr << 6) + (mi << 4) + (quad << 2) + r];
    }
    __syncthreads();
  }
}

__global__ void __launch_bounds__(256, 2) kway_bf16_kernel(
    const short* __restrict__ Wbf,   // [38][1152][1152]
    const short* __restrict__ Sbf,   // [50048][1152]
    const short* __restrict__ Ebf,   // [50048][1152]
    float* __restrict__ out)
{
  __shared__ short lds_a[2 * BM * BJ];        // 16 KB: 2 buffers x 8 KB
  __shared__ short lds_b[2 * 2 * BM * BJ];    // 32 KB: 2 buffers x (PP=2) 16 KB
  __shared__ float lds_red[BM];               // 512 B cross-wave combine

  const int e  = blockIdx.x / NTILES;     // e-major: W_e stays L2-hot per XCD
  const int it = blockIdx.x % NTILES;
  const int i0 = it * BM;

  const int tid  = threadIdx.x;
  const int wave = tid >> 6;
  const int lane = tid & 63;

  const short* Abase = Ebf + (size_t)i0 * FPAD;
  const short* Bbase = Wbf + (size_t)e * FPAD * FPAD;
  const short* Sbase = Sbf + (size_t)i0 * FPAD;

  float out_acc[16];
#pragma unroll
  for (int x = 0; x < 16; ++x) out_acc[x] = 0.f;

  // k groups: 4 x (PP=2, 256 rows) + 1 x (PP=1, 128 rows) = 1152
  for (int g = 0; g < 4; ++g)
    nc_group<2>(Abase, Bbase, Sbase, out_acc, lds_a, lds_b, lds_red,
                g << 8, wave, lane);
  nc_group<1>(Abase, Bbase, Sbase, out_acc, lds_a, lds_b, lds_red,
              1024, wave, lane);

  // wc==0 waves (0 and 2) hold the full sums for rows wr*64 .. wr*64+63
  if ((wave & 1) == 0 && (lane & 15) == 0) {
    const int wr = wave >> 1;
    const int quad = lane >> 4;
#pragma unroll
    for (int mi = 0; mi < 4; ++mi)
#pragma unroll
      for (int r = 0; r < 4; ++r) {
        const int gi = i0 + (wr << 6) + (mi << 4) + (quad << 2) + r;
        if (gi < NPAIRS) out[(size_t)e * NPAIRS + gi] = out_acc[(mi << 2) + r];
      }
  }
}

// ================= fallback fp32 path (round-1 kernel, known-good) =========
#define LSTRIDE 40
__global__ void __launch_bounds__(256) kway_fp32_kernel(
    const float* __restrict__ start_emb,
    const float* __restrict__ end_emb,
    const float* __restrict__ weights,
    float* __restrict__ out)
{
  __shared__ short lds_a[BM * LSTRIDE];
  __shared__ short lds_b[BN * LSTRIDE];

  const int e  = blockIdx.x % NUM_E;
  const int it = blockIdx.x / NUM_E;
  const int i0 = it * BM;

  const int tid  = threadIdx.x;
  const int wave = tid >> 6;
  const int lane = tid & 63;
  const int l15  = lane & 15;
  const int quad = lane >> 4;

  const float* We = weights + (size_t)e * FDIM * FDIM;
  const int srow = tid >> 3;
  const int scol = (tid & 7) << 2;

  float out_acc[8];
#pragma unroll
  for (int x = 0; x < 8; ++x) out_acc[x] = 0.f;

  for (int nc = 0; nc < NCHUNK; ++nc) {
    const int k0 = nc * BN;
    float4v acc[2][8];
#pragma unroll
    for (int mi = 0; mi < 2; ++mi)
#pragma unroll
      for (int ni = 0; ni < 8; ++ni)
        acc[mi][ni] = (float4v){0.f, 0.f, 0.f, 0.f};

    for (int jt = 0; jt < NJIT; ++jt) {
      const int gj = jt * BJ + scol;
      const bool jok = gj < FDIM;
      float4v av[4], bv[4];
#pragma unroll
      for (int rr = 0; rr < 4; ++rr) {
        const int row = (rr << 5) + srow;
        const int gi = i0 + row;
        av[rr] = (float4v){0.f, 0.f, 0.f, 0.f};
        if (jok && gi < NPAIRS)
          av[rr] = *(const float4v*)(end_emb + (size_t)gi * FDIM + gj);
        const int gk = k0 + row;
        bv[rr] = (float4v){0.f, 0.f, 0.f, 0.f};
        if (jok && gk < FDIM)
          bv[rr] = *(const float4v*)(We + (size_t)gk * FDIM + gj);
      }
#pragma unroll
      for (int rr = 0; rr < 4; ++rr) {
        const int row = (rr << 5) + srow;
        short4v a4 = { f2bf(av[rr][0]), f2bf(av[rr][1]), f2bf(av[rr][2]), f2bf(av[rr][3]) };
        *(short4v*)(&lds_a[row * LSTRIDE + scol]) = a4;
        short4v b4 = { f2bf(bv[rr][0]), f2bf(bv[rr][1]), f2bf(bv[rr][2]), f2bf(bv[rr][3]) };
        *(short4v*)(&lds_b[row * LSTRIDE + scol]) = b4;
      }
      __syncthreads();

      short8 afrag[2], bfrag[8];
#pragma unroll
      for (int mi = 0; mi < 2; ++mi)
        afrag[mi] = *(short8*)(&lds_a[((wave << 5) + (mi << 4) + l15) * LSTRIDE + (quad << 3)]);
#pragma unroll
      for (int ni = 0; ni < 8; ++ni)
        bfrag[ni] = *(short8*)(&lds_b[((ni << 4) + l15) * LSTRIDE + (quad << 3)]);
#pragma unroll
      for (int mi = 0; mi < 2; ++mi)
#pragma unroll
        for (int ni = 0; ni < 8; ++ni)
          acc[mi][ni] = __builtin_amdgcn_mfma_f32_16x16x32_bf16(
              afrag[mi], bfrag[ni], acc[mi][ni], 0, 0, 0);
      __syncthreads();
    }

#pragma unroll
    for (int mi = 0; mi < 2; ++mi) {
#pragma unroll
      for (int r = 0; r < 4; ++r) {
        const int gi = i0 + (wave << 5) + (mi << 4) + (quad << 2) + r;
        const bool iok = gi < NPAIRS;
        float s = 0.f;
#pragma unroll
        for (int ni = 0; ni < 8; ++ni) {
          const int k = k0 + (ni << 4) + l15;
          const float sv = (iok && k < FDIM) ? start_emb[(size_t)gi * FDIM + k] : 0.f;
          s += acc[mi][ni][r] * sv;
        }
        out_acc[(mi << 2) + r] += s;
      }
    }
  }

#pragma unroll
  for (int x = 0; x < 8; ++x) {
    float v = out_acc[x];
    v += __shfl_xor(v, 1);
    v += __shfl_xor(v, 2);
    v += __shfl_xor(v, 4);
    v += __shfl_xor(v, 8);
    out_acc[x] = v;
  }
  if (l15 == 0) {
#pragma unroll
    for (int mi = 0; mi < 2; ++mi)
#pragma unroll
      for (int r = 0; r < 4; ++r) {
        const int gi = i0 + (wave << 5) + (mi << 4) + (quad << 2) + r;
        if (gi < NPAIRS) out[(size_t)e * NPAIRS + gi] = out_acc[(mi << 2) + r];
      }
  }
}

extern "C" void kernel_launch(void* const* d_in, const int* in_sizes, int n_in,
                              void* d_out, int out_size, void* d_ws, size_t ws_size,
                              hipStream_t stream) {
  const float* start_emb = (const float*)d_in[0];
  const float* end_emb   = (const float*)d_in[1];
  const float* weights   = (const float*)d_in[2];
  float* out = (float*)d_out;

  const size_t W_ELEMS = (size_t)NUM_E * FPAD * FPAD;   // 50,429,952
  const size_t EMB_ELEMS = (size_t)NPAD * FPAD;         // 57,655,296
  const size_t need = (W_ELEMS + 2 * EMB_ELEMS) * sizeof(short);  // ~331.5 MB

  if (ws_size >= need) {
    short* Wbf = (short*)d_ws;
    short* Sbf = Wbf + W_ELEMS;
    short* Ebf = Sbf + EMB_ELEMS;

    {
      const long wt = (long)NUM_E * FPAD * (FPAD >> 3);
      convpad_kernel<<<(int)((wt + 255) / 256), 256, 0, stream>>>(
          weights, Wbf, FDIM, FPAD, FDIM, FPAD, NUM_E);
      const long et = (long)NPAD * (FPAD >> 3);
      convpad_kernel<<<(int)((et + 255) / 256), 256, 0, stream>>>(
          start_emb, Sbf, NPAIRS, NPAD, FDIM, FPAD, 1);
      convpad_kernel<<<(int)((et + 255) / 256), 256, 0, stream>>>(
          end_emb, Ebf, NPAIRS, NPAD, FDIM, FPAD, 1);
    }
    kway_bf16_kernel<<<NUM_E * NTILES, 256, 0, stream>>>(Wbf, Sbf, Ebf, out);
  } else {
    kway_fp32_kernel<<<NUM_E * NTILES, 256, 0, stream>>>(
        start_emb, end_emb, weights, out);
  }
}